// Round 15
// baseline (76.568 us; speedup 1.0000x reference)
//
#include <hip/hip_runtime.h>
#include <math.h>

#define S_    10
#define C_    48
#define HWD   64
#define M_    512
#define PADK  4
#define PAIRS 20           // S_ * N(=2)

// Compact gathered RAW y layout: GY[(s*96 + 2*c + n)*512 + m]
// ws layout (float offsets)
#define OFF_GY  0
#define OFF_CM  491520                    // colmax (uint-encoded floats), 10240
#define OFF_MU  (OFF_CM + PAIRS * M_)     // 480 floats (channel SUMS; /1024 at use)
#define OFF_CNT (OFF_MU + 480)            // 20 uint pair-arrival counters
#define OFF_ALL (OFF_CNT + 20)            // 1 uint global pair-done counter
#define OFF_PL  (OFF_ALL + 1)             // 20 float pair losses
#define OFF_YS  (((OFF_PL + 20) + 3) & ~3) // 10240 col scales (16B aligned)
#define ZERO_N  (10240 + 480 + 20 + 1 + 20)   // OFF_CM..OFF_PL contiguous

__device__ __forceinline__ int gidx(int n, int c, int h, int w, int d) {
  return (((n * C_ + c) * HWD + h) * HWD + w) * HWD + d;
}

// ---- kernel 1: gather y -> compact GY; channel sums via 2 atomicAdds ------
// 960 blocks x 256 thr; block = ((s,c), n). 2-partial float sum: a+b==b+a.
__global__ void k_gy(const float* __restrict__ y, const int* __restrict__ hi,
                     const int* __restrict__ wi, const int* __restrict__ di,
                     float* __restrict__ ws) {
  int b = blockIdx.x, t = threadIdx.x;
  int lane = t & 63, wv = t >> 6;
  int slice = b >> 1, half = b & 1;                  // half = n
  int s = slice / C_, c = slice % C_;
  int h0 = hi[s] - PADK, w0 = wi[s] - PADK, d0 = di[s] - PADK;
  float* dst = ws + OFF_GY + (s * 96 + 2 * c + half) * 512;
  float sum = 0.f;
#pragma unroll
  for (int j = 0; j < 2; ++j) {
    int m = t + 256 * j;
    float v = y[gidx(half, c, h0 + (m >> 6), w0 + ((m >> 3) & 7), d0 + (m & 7))];
    dst[m] = v;                        // coalesced compact store
    sum += v;
  }
  __shared__ float red[4];
#pragma unroll
  for (int off = 32; off; off >>= 1) sum += __shfl_xor(sum, off);
  if (lane == 0) red[wv] = sum;
  __syncthreads();
  if (t == 0)
    atomicAdd(ws + OFF_MU + s * C_ + c, red[0] + red[1] + red[2] + red[3]);
}

// ---- kernel 2: per-column y scales only (no 2MB rewrite) ------------------
// 160 blocks x 256 thr; 4 lanes per column (12 channels each). L2-resident.
__global__ void k_ysc(float* __restrict__ ws) {
  int g = blockIdx.x * 256 + threadIdx.x;   // 0..40959
  int col = g >> 2;                         // 0..10239 = pair*512 + m
  int q = threadIdx.x & 3;                  // channel quarter
  int pair = col >> 9, m = col & 511;
  int s = pair >> 1, n = pair & 1;
  const float* base = ws + OFF_GY + (s * 96 + n) * 512 + m;
  const float* mus = ws + OFF_MU + s * C_;
  int c0 = q * 12;
  float ss = 0.f;
#pragma unroll
  for (int j = 0; j < 12; ++j) {
    float v = base[(c0 + j) * 1024] - mus[c0 + j] * (1.0f / 1024.0f);
    ss += v * v;
  }
  ss += __shfl_xor(ss, 1);             // combine 4 quarters (aligned group)
  ss += __shfl_xor(ss, 2);
  if (q == 0) ws[OFF_YS + col] = 1.0f / fmaxf(sqrtf(ss), 1e-12f);
}

// ---- kernel 3: x inline-gather+norm; y staged (center+scale fused); -------
//      dist + row-softmax + colmax + fused final.
// 320 blocks x 512 thr (8 waves); block = (pair, tile of 32 rows); wave owns
// 4 rows (acc[4][8]). y per channel consumed as 2x ds_read_b128
// (p = 4*lane+k | 256+4*lane+(k-4)); 2 chunks of 24 channels (2 barrier pairs).
// LDS ~58KB -> 2 blocks/CU packable; 2.5 waves/SIMD avg.
__global__ __launch_bounds__(512, 2) void k_main(const float* __restrict__ x,
                                                 const int* __restrict__ hi,
                                                 const int* __restrict__ wi,
                                                 const int* __restrict__ di,
                                                 float* __restrict__ ws,
                                                 float* __restrict__ out) {
  int b = blockIdx.x;
  int pair = b >> 4, tile = b & 15;
  int s = pair >> 1, n = pair & 1;
  int t = threadIdx.x, lane = t & 63, wv = t >> 6;

  __shared__ float xs[C_ * 32];        // x tile [c][r] (32 rows), 6KB
  __shared__ float ybuf[24 * 512];     // y chunk [cr][p], 48KB
  __shared__ float mus[C_];
  __shared__ unsigned cm[M_];          // block colmax (uint bits)
  __shared__ float red[8];
  __shared__ unsigned arr;
  __shared__ int lastflag;

  int h0 = hi[s] - PADK, w0 = wi[s] - PADK, d0 = di[s] - PADK;
  if (t < C_) mus[t] = ws[OFF_MU + s * C_ + t] * (1.0f / 1024.0f);
  cm[t] = 0u;                          // t covers all 512 p slots

  // stage raw x tile: 1536 elems; i -> (c = i>>5, r = i&31), m = tile*32+r
#pragma unroll
  for (int j = 0; j < 3; ++j) {
    int i = t + 512 * j;
    int c = i >> 5, r = i & 31;
    int m = tile * 32 + r;
    xs[c * 32 + r] =
        x[gidx(n, c, h0 + (m >> 6), w0 + ((m >> 3) & 7), d0 + (m & 7))];
  }
  __syncthreads();

  // center + per-column normalize x: 16-thread group per column (32 cols).
  {
    int col = t >> 4, sub = t & 15;    // sub covers channels sub, sub+16, sub+32
    float v0 = xs[sub * 32 + col] - mus[sub];
    float v1 = xs[(sub + 16) * 32 + col] - mus[sub + 16];
    float v2 = xs[(sub + 32) * 32 + col] - mus[sub + 32];
    float ss = v0 * v0 + v1 * v1 + v2 * v2;
    ss += __shfl_xor(ss, 8); ss += __shfl_xor(ss, 4);
    ss += __shfl_xor(ss, 2); ss += __shfl_xor(ss, 1);
    float sc = 1.0f / fmaxf(sqrtf(ss), 1e-12f);
    xs[sub * 32 + col] = v0 * sc;
    xs[(sub + 16) * 32 + col] = v1 * sc;
    xs[(sub + 32) * 32 + col] = v2 * sc;
  }

  float acc[4][8];
#pragma unroll
  for (int r = 0; r < 4; ++r)
#pragma unroll
    for (int k = 0; k < 8; ++k) acc[r][k] = 0.f;

  const float* gy = ws + OFF_GY + (s * 96 + n) * 512;
  const float* ysc = ws + OFF_YS + pair * 512;
  for (int chunk = 0; chunk < 2; ++chunk) {
    __syncthreads();                   // x-norm done / prev chunk consumed
#pragma unroll
    for (int i2 = 0; i2 < 6; ++i2) {   // stage 24 ch: 3072 float4s, fused norm
      int li = t + 512 * i2;
      int cr = li >> 7, p4 = (li & 127) << 2;
      int c = chunk * 24 + cr;
      float4 v = *(const float4*)(gy + c * 1024 + p4);
      float4 s4 = *(const float4*)(ysc + p4);
      float mu = mus[c];
      float4 o;
      o.x = (v.x - mu) * s4.x; o.y = (v.y - mu) * s4.y;
      o.z = (v.z - mu) * s4.z; o.w = (v.w - mu) * s4.w;
      *(float4*)(ybuf + cr * 512 + p4) = o;
    }
    __syncthreads();
#pragma unroll
    for (int cr = 0; cr < 24; ++cr) {
      float4 y0 = *(const float4*)(ybuf + cr * 512 + 4 * lane);        // b128
      float4 y1 = *(const float4*)(ybuf + cr * 512 + 256 + 4 * lane);  // b128
      int c = chunk * 24 + cr;
      float4 xv = *(const float4*)(xs + c * 32 + wv * 4);  // wave-uniform bcast
      acc[0][0] += xv.x * y0.x; acc[0][1] += xv.x * y0.y;
      acc[0][2] += xv.x * y0.z; acc[0][3] += xv.x * y0.w;
      acc[0][4] += xv.x * y1.x; acc[0][5] += xv.x * y1.y;
      acc[0][6] += xv.x * y1.z; acc[0][7] += xv.x * y1.w;
      acc[1][0] += xv.y * y0.x; acc[1][1] += xv.y * y0.y;
      acc[1][2] += xv.y * y0.z; acc[1][3] += xv.y * y0.w;
      acc[1][4] += xv.y * y1.x; acc[1][5] += xv.y * y1.y;
      acc[1][6] += xv.y * y1.z; acc[1][7] += xv.y * y1.w;
      acc[2][0] += xv.z * y0.x; acc[2][1] += xv.z * y0.y;
      acc[2][2] += xv.z * y0.z; acc[2][3] += xv.z * y0.w;
      acc[2][4] += xv.z * y1.x; acc[2][5] += xv.z * y1.y;
      acc[2][6] += xv.z * y1.z; acc[2][7] += xv.z * y1.w;
      acc[3][0] += xv.w * y0.x; acc[3][1] += xv.w * y0.y;
      acc[3][2] += xv.w * y0.z; acc[3][3] += xv.w * y0.w;
      acc[3][4] += xv.w * y1.x; acc[3][5] += xv.w * y1.y;
      acc[3][6] += xv.w * y1.z; acc[3][7] += xv.w * y1.w;
    }
  }

  // epilogue: per-row min -> softmax -> wave colmax (p = 4*lane+k mapping)
  float cm2[8];
#pragma unroll
  for (int k = 0; k < 8; ++k) cm2[k] = 0.f;
#pragma unroll
  for (int r = 0; r < 4; ++r) {
    float dmin = 3.4e38f;
#pragma unroll
    for (int k = 0; k < 8; ++k) {
      float d = 1.0f - acc[r][k];
      acc[r][k] = d;
      dmin = fminf(dmin, d);
    }
#pragma unroll
    for (int off = 32; off; off >>= 1) dmin = fminf(dmin, __shfl_xor(dmin, off));
    float inv = 2.0f / (dmin + 1e-5f); // logits <= 2, no overflow
    float e[8], sm = 0.f;
#pragma unroll
    for (int k = 0; k < 8; ++k) {
      e[k] = __expf(2.0f - acc[r][k] * inv);
      sm += e[k];
    }
#pragma unroll
    for (int off = 32; off; off >>= 1) sm += __shfl_xor(sm, off);
    float rs = 1.0f / sm;
#pragma unroll
    for (int k = 0; k < 8; ++k) cm2[k] = fmaxf(cm2[k], e[k] * rs);
  }
#pragma unroll
  for (int k = 0; k < 4; ++k)          // p = 4*lane + k
    atomicMax(&cm[4 * lane + k], __float_as_uint(cm2[k]));
#pragma unroll
  for (int k = 4; k < 8; ++k)          // p = 256 + 4*lane + (k-4)
    atomicMax(&cm[256 + 4 * lane + (k - 4)], __float_as_uint(cm2[k]));
  __syncthreads();

  unsigned* cmu = (unsigned*)(ws + OFF_CM) + pair * M_;
  if (cm[t]) atomicMax(&cmu[t], cm[t]);   // 1 global atomic per thread

  // ---- fused final: last block per pair reduces; last pair writes out ----
  __threadfence();
  if (t == 0) arr = atomicAdd((unsigned*)(ws + OFF_CNT) + pair, 1u);
  __syncthreads();
  if (arr == 15) {
    float sum = __uint_as_float(atomicOr(&cmu[t], 0u));   // coherent read
#pragma unroll
    for (int off = 32; off; off >>= 1) sum += __shfl_xor(sum, off);
    if (lane == 0) red[wv] = sum;
    if (t == 0) lastflag = 0;
    __syncthreads();
    if (t == 0) {
      float tot = 0.f;
#pragma unroll
      for (int i = 0; i < 8; ++i) tot += red[i];
      float loss = -logf(tot * (1.0f / 512.0f) + 1e-5f);
      atomicExch((unsigned*)(ws + OFF_PL) + pair, __float_as_uint(loss));
      __threadfence();
      unsigned d = atomicAdd((unsigned*)(ws + OFF_ALL), 1u);
      if (d == PAIRS - 1) lastflag = 1;
    }
    __syncthreads();
    if (lastflag && t < 32) {          // parallel 20-loss readback
      float v = (t < PAIRS)
                    ? __uint_as_float(atomicOr((unsigned*)(ws + OFF_PL) + t, 0u))
                    : 0.f;
#pragma unroll
      for (int off = 16; off; off >>= 1) v += __shfl_xor(v, off);
      if (t == 0) out[0] = v * (1.0f / (float)PAIRS);
    }
  }
}

extern "C" void kernel_launch(void* const* d_in, const int* in_sizes, int n_in,
                              void* d_out, int out_size, void* d_ws, size_t ws_size,
                              hipStream_t stream) {
  const float* x = (const float*)d_in[0];
  const float* y = (const float*)d_in[1];
  const int* hi = (const int*)d_in[2];
  const int* wi = (const int*)d_in[3];
  const int* di = (const int*)d_in[4];
  float* ws = (float*)d_ws;
  float* out = (float*)d_out;

  hipMemsetAsync(ws + OFF_CM, 0, ZERO_N * sizeof(float), stream);
  k_gy<<<960, 256, 0, stream>>>(y, hi, wi, di, ws);
  k_ysc<<<160, 256, 0, stream>>>(ws);
  k_main<<<PAIRS * 16, 512, 0, stream>>>(x, hi, wi, di, ws, out);
}

// Round 16
// 41.632 us; speedup vs baseline: 1.8392x; 1.8392x over previous
//
#include <hip/hip_runtime.h>
#include <hip/hip_bf16.h>
#include <math.h>

#define S_    10
#define C_    48
#define HWD   64
#define M_    512
#define PADK  4
#define PAIRS 20           // S_ * N(=2)
#define KP    72           // bf16 K-pitch (144B: 16B-aligned, 2-way bank alias = free)

// ws layout (float offsets)
#define OFF_GY  0                         // raw y compact fp32, c-major
#define OFF_GX  491520                    // raw x compact fp32, c-major
#define OFF_CM  983040                    // colmax (uint bits), 10240
#define OFF_MU  (OFF_CM + PAIRS * M_)     // 480 floats (channel MEANS)
#define OFF_CNT (OFF_MU + 480)            // 20 uint pair-arrival counters
#define OFF_ALL (OFF_CNT + 20)            // 1 uint pair-done counter
#define OFF_PL  (OFF_ALL + 1)             // 20 float pair losses
#define ZERO_N  (10240 + 480 + 20 + 1 + 20)
#define OFF_YK  993804                    // bf16 K-major y: 10240 cols x KP ushorts
#define OFF_XK  (OFF_YK + 368640)         // bf16 K-major x (368640 floats each)

typedef __attribute__((ext_vector_type(8))) short bf16x8;
typedef __attribute__((ext_vector_type(4))) float f32x4;

__device__ __forceinline__ int gidx(int n, int c, int h, int w, int d) {
  return (((n * C_ + c) * HWD + h) * HWD + w) * HWD + d;
}

__device__ __forceinline__ unsigned short f2bf(float f) {  // RNE bf16
  unsigned u = __float_as_uint(f);
  u += 0x7FFFu + ((u >> 16) & 1u);
  return (unsigned short)(u >> 16);
}

// ---- kernel 1: gather x,y -> compact fp32; y channel means (R8, proven) ---
__global__ void k_gather(const float* __restrict__ x, const float* __restrict__ y,
                         const int* __restrict__ hi, const int* __restrict__ wi,
                         const int* __restrict__ di, float* __restrict__ ws) {
  int b = blockIdx.x, t = threadIdx.x;
  int lane = t & 63, wv = t >> 6;
  __shared__ float red[4];
  int which = b >= 480;                              // 0 = y, 1 = x
  int r = which ? b - 480 : b;
  int s = r / C_, c = r % C_;
  const float* src = which ? x : y;
  int h0 = hi[s] - PADK, w0 = wi[s] - PADK, d0 = di[s] - PADK;
  float* dst = ws + (which ? OFF_GX : OFF_GY) + (s * 96 + 2 * c) * 512;
  float sum = 0.f;
#pragma unroll
  for (int j = 0; j < 4; ++j) {
    int i = t + 256 * j;
    int n = i >> 9, m = i & 511;
    float v = src[gidx(n, c, h0 + (m >> 6), w0 + ((m >> 3) & 7), d0 + (m & 7))];
    dst[n * 512 + m] = v;
    sum += v;
  }
  if (!which) {
#pragma unroll
    for (int off = 32; off; off >>= 1) sum += __shfl_xor(sum, off);
    if (lane == 0) red[wv] = sum;
    __syncthreads();
    if (t == 0)
      ws[OFF_MU + s * C_ + c] =
          (red[0] + red[1] + red[2] + red[3]) * (1.0f / 1024.0f);
  }
}

// ---- kernel 2: center + normalize -> bf16 K-major (pitch KP, k>=48 zero) --
// 320 blocks x 256 thr; 4 lanes per column (12 channels each). Proven indexing.
__global__ void k_nc(float* __restrict__ ws) {
  int g = blockIdx.x * 256 + threadIdx.x;   // 0..81919
  int col = g >> 2;                         // 0..20479
  int q = threadIdx.x & 3;
  int which = col >= 10240;                 // 0 = y, 1 = x
  int cix = which ? col - 10240 : col;
  int pair = cix >> 9, m = cix & 511;
  int s = pair >> 1, n = pair & 1;
  const float* base = ws + (which ? OFF_GX : OFF_GY) + (s * 96 + n) * 512 + m;
  const float* mus = ws + OFF_MU + s * C_;
  int c0 = q * 12;
  float v[12], ss = 0.f;
#pragma unroll
  for (int j = 0; j < 12; ++j) {
    v[j] = base[(c0 + j) * 1024] - mus[c0 + j];
    ss += v[j] * v[j];
  }
  ss += __shfl_xor(ss, 1);
  ss += __shfl_xor(ss, 2);
  float sc = 1.0f / fmaxf(sqrtf(ss), 1e-12f);
  unsigned short* dstk = (unsigned short*)(ws + (which ? OFF_XK : OFF_YK)) +
                         (cix * KP) + c0;
#pragma unroll
  for (int j = 0; j < 12; ++j) dstk[j] = f2bf(v[j] * sc);
  if (q == 3) {                         // zero k = 48..63 (frag pad)
#pragma unroll
    for (int j = 12; j < 28; ++j) dstk[j] = 0;
  }
}

// ---- kernel 3: MFMA dist + row-softmax + colmax + fused final -------------
// 160 blocks x 256 thr (4 waves); block = (pair, 64-row slab); wave = 16 rows
// x full 512 cols. dist tile regs f32x4 d[32] (static idx). C/D mapping per
// m89: col = lane&15, row = (lane>>4)*4 + reg.
__global__ __launch_bounds__(256, 2) void k_mm(float* __restrict__ ws,
                                               float* __restrict__ out) {
  int b = blockIdx.x;
  int pair = b >> 3, rblk = b & 7;
  int t = threadIdx.x, lane = t & 63, wv = t >> 6;
  int row16 = lane & 15, kg = lane >> 4;

  __shared__ __align__(16) unsigned short xk[64 * KP];    // 9.2KB
  __shared__ __align__(16) unsigned short yk[256 * KP];   // 36.9KB
  __shared__ unsigned cm[M_];
  __shared__ float red[4];
  __shared__ unsigned arr;
  __shared__ int lastflag;

  cm[t] = 0u; cm[t + 256] = 0u;

  const unsigned short* xku = (const unsigned short*)(ws + OFF_XK);
  const unsigned short* yku = (const unsigned short*)(ws + OFF_YK);

  // stage x slab: 64 rows x KP = 4608 ushorts = 576 float4 (contiguous)
  {
    const float4* g4 = (const float4*)(xku + (pair * 512 + rblk * 64) * KP);
    float4* l4 = (float4*)xk;
#pragma unroll
    for (int j = 0; j < 3; ++j) {
      int i = t + 256 * j;
      if (i < 576) l4[i] = g4[i];
    }
  }
  __syncthreads();

  const unsigned short* xrow = xk + (wv * 16 + row16) * KP + kg * 8;
  bf16x8 a0 = *(const bf16x8*)(xrow);        // k = kg*8 .. +7
  bf16x8 a1 = *(const bf16x8*)(xrow + 32);   // k = 32 + kg*8 .. +7

  f32x4 d[32];
#pragma unroll
  for (int chunk = 0; chunk < 2; ++chunk) {
    __syncthreads();                   // prev chunk consumed / a-frags loaded
    {                                  // stage 256 cols: 2304 float4
      const float4* g4 =
          (const float4*)(yku + (pair * 512 + chunk * 256) * KP);
      float4* l4 = (float4*)yk;
#pragma unroll
      for (int j = 0; j < 9; ++j) l4[t + 256 * j] = g4[t + 256 * j];
    }
    __syncthreads();
#pragma unroll
    for (int ct2 = 0; ct2 < 16; ++ct2) {
      const unsigned short* yrow = yk + (ct2 * 16 + row16) * KP + kg * 8;
      bf16x8 b0 = *(const bf16x8*)(yrow);
      bf16x8 b1 = *(const bf16x8*)(yrow + 32);
      f32x4 z = {0.f, 0.f, 0.f, 0.f};
      f32x4 dd = __builtin_amdgcn_mfma_f32_16x16x32_bf16(a0, b0, z, 0, 0, 0);
      d[chunk * 16 + ct2] =
          __builtin_amdgcn_mfma_f32_16x16x32_bf16(a1, b1, dd, 0, 0, 0);
    }
  }

  // epilogue: amax per row (dmin = 1 - amax), softmax in place, colmax
  float am0 = -3.4e38f, am1 = -3.4e38f, am2 = -3.4e38f, am3 = -3.4e38f;
#pragma unroll
  for (int ct = 0; ct < 32; ++ct) {
    am0 = fmaxf(am0, d[ct][0]); am1 = fmaxf(am1, d[ct][1]);
    am2 = fmaxf(am2, d[ct][2]); am3 = fmaxf(am3, d[ct][3]);
  }
#pragma unroll
  for (int off = 1; off < 16; off <<= 1) {
    am0 = fmaxf(am0, __shfl_xor(am0, off));
    am1 = fmaxf(am1, __shfl_xor(am1, off));
    am2 = fmaxf(am2, __shfl_xor(am2, off));
    am3 = fmaxf(am3, __shfl_xor(am3, off));
  }
  float inv0 = 2.f / ((1.f - am0) + 1e-5f), c20 = 2.f - inv0;
  float inv1 = 2.f / ((1.f - am1) + 1e-5f), c21 = 2.f - inv1;
  float inv2 = 2.f / ((1.f - am2) + 1e-5f), c22 = 2.f - inv2;
  float inv3 = 2.f / ((1.f - am3) + 1e-5f), c23 = 2.f - inv3;
  float sm0 = 0.f, sm1 = 0.f, sm2 = 0.f, sm3 = 0.f;
#pragma unroll
  for (int ct = 0; ct < 32; ++ct) {    // logit = 2 - (1-a)*inv = c2 + a*inv
    float e0 = __expf(fmaf(d[ct][0], inv0, c20));
    float e1 = __expf(fmaf(d[ct][1], inv1, c21));
    float e2 = __expf(fmaf(d[ct][2], inv2, c22));
    float e3 = __expf(fmaf(d[ct][3], inv3, c23));
    d[ct][0] = e0; d[ct][1] = e1; d[ct][2] = e2; d[ct][3] = e3;
    sm0 += e0; sm1 += e1; sm2 += e2; sm3 += e3;
  }
#pragma unroll
  for (int off = 1; off < 16; off <<= 1) {
    sm0 += __shfl_xor(sm0, off); sm1 += __shfl_xor(sm1, off);
    sm2 += __shfl_xor(sm2, off); sm3 += __shfl_xor(sm3, off);
  }
  float rs0 = 1.f / sm0, rs1 = 1.f / sm1, rs2 = 1.f / sm2, rs3 = 1.f / sm3;
#pragma unroll
  for (int ct = 0; ct < 32; ++ct) {
    float cc = fmaxf(fmaxf(d[ct][0] * rs0, d[ct][1] * rs1),
                     fmaxf(d[ct][2] * rs2, d[ct][3] * rs3));
    cc = fmaxf(cc, __shfl_xor(cc, 16));
    cc = fmaxf(cc, __shfl_xor(cc, 32));  // all 16 wave-rows combined
    if (lane < 16) atomicMax(&cm[ct * 16 + lane], __float_as_uint(cc));
  }
  __syncthreads();

  unsigned* cmu = (unsigned*)(ws + OFF_CM) + pair * M_;
  if (cm[t]) atomicMax(&cmu[t], cm[t]);
  if (cm[t + 256]) atomicMax(&cmu[t + 256], cm[t + 256]);

  // ---- fused final (proven tail; 8 blocks/pair -> arr == 7) --------------
  __threadfence();
  if (t == 0) arr = atomicAdd((unsigned*)(ws + OFF_CNT) + pair, 1u);
  __syncthreads();
  if (arr == 7) {
    float sum = __uint_as_float(atomicOr(&cmu[t], 0u)) +
                __uint_as_float(atomicOr(&cmu[t + 256], 0u));
#pragma unroll
    for (int off = 32; off; off >>= 1) sum += __shfl_xor(sum, off);
    if (lane == 0) red[wv] = sum;
    if (t == 0) lastflag = 0;
    __syncthreads();
    if (t == 0) {
      float tot = red[0] + red[1] + red[2] + red[3];
      float loss = -logf(tot * (1.0f / 512.0f) + 1e-5f);
      atomicExch((unsigned*)(ws + OFF_PL) + pair, __float_as_uint(loss));
      __threadfence();
      unsigned dct = atomicAdd((unsigned*)(ws + OFF_ALL), 1u);
      if (dct == PAIRS - 1) lastflag = 1;
    }
    __syncthreads();
    if (lastflag && t < 32) {
      float v = (t < PAIRS)
                    ? __uint_as_float(atomicOr((unsigned*)(ws + OFF_PL) + t, 0u))
                    : 0.f;
#pragma unroll
      for (int off = 16; off; off >>= 1) v += __shfl_xor(v, off);
      if (t == 0) out[0] = v * (1.0f / (float)PAIRS);
    }
  }
}

extern "C" void kernel_launch(void* const* d_in, const int* in_sizes, int n_in,
                              void* d_out, int out_size, void* d_ws, size_t ws_size,
                              hipStream_t stream) {
  const float* x = (const float*)d_in[0];
  const float* y = (const float*)d_in[1];
  const int* hi = (const int*)d_in[2];
  const int* wi = (const int*)d_in[3];
  const int* di = (const int*)d_in[4];
  float* ws = (float*)d_ws;
  float* out = (float*)d_out;

  hipMemsetAsync(ws + OFF_CM, 0, ZERO_N * sizeof(float), stream);
  k_gather<<<960, 256, 0, stream>>>(x, y, hi, wi, di, ws);
  k_nc<<<320, 256, 0, stream>>>(ws);
  k_mm<<<PAIRS * 8, 256, 0, stream>>>(ws, out);
}